// Round 4
// baseline (202.758 us; speedup 1.0000x reference)
//
#include <hip/hip_runtime.h>
#include <cstdint>
#include <cstddef>

// Qwen3AttentionModified: B=1 S=2048 D=2048 H=16 KVH=8 HD=128
// cast hs->bf16; transpose+cast weights; QKV GEMM (+XCD swizzle); RoPE -> Q/K bf16;
// V -> bf16 [kvh][d][s]; attention: 128-key chunks, 1 raw-barrier/chunk (no vmcnt
// drain), K/V reg-staged with cross-barrier prefetch, P double-buffered LDS,
// 1024 LPT-ordered blocks; O GEMM (BM=64) -> fp32 d_out.

namespace {
constexpr int kS = 2048;
constexpr int kD = 2048;
constexpr int kH = 16;
constexpr int kKVH = 8;
constexpr int kHD = 128;
constexpr float kScale = 0.08838834764831845f;  // 128^-0.5
constexpr size_t MB = 1u << 20;
}  // namespace

using f32x4 = __attribute__((ext_vector_type(4))) float;
using bfrag = __attribute__((ext_vector_type(8))) short;   // 8 x bf16 (4 VGPR)
using float4v = __attribute__((ext_vector_type(4))) float;
using short4v = __attribute__((ext_vector_type(4))) short;

__device__ __forceinline__ unsigned short f2b(float f) {
  union { float f; unsigned u; } x; x.f = f;
  unsigned r = x.u + 0x7FFFu + ((x.u >> 16) & 1u);  // RNE
  return (unsigned short)(r >> 16);
}

__device__ __forceinline__ void gload_lds16(const void* g, void* l) {
  __builtin_amdgcn_global_load_lds(
      (const __attribute__((address_space(1))) unsigned*)g,
      (__attribute__((address_space(3))) unsigned*)l, 16, 0, 0);
}

// ---------------- cast fp32 -> bf16 ----------------
__global__ __launch_bounds__(256) void qwen_cast_bf16(const float* __restrict__ in,
                                                      unsigned short* __restrict__ out,
                                                      int n4) {
  int i = blockIdx.x * 256 + threadIdx.x;
  if (i >= n4) return;
  float4v v = *(const float4v*)(in + (size_t)i * 4);
  short4v o;
  o[0] = (short)f2b(v[0]); o[1] = (short)f2b(v[1]);
  o[2] = (short)f2b(v[2]); o[3] = (short)f2b(v[3]);
  *(short4v*)(out + (size_t)i * 4) = o;
}

// ------------- transpose + cast: fp32 [R][C] -> bf16 [C][ldo] -------------
__global__ __launch_bounds__(256) void qwen_tw(const float* __restrict__ in, int R, int C,
                                               unsigned short* __restrict__ out, int ldo) {
  __shared__ float t[64][65];
  int c0 = blockIdx.x * 64, r0 = blockIdx.y * 64;
  int tr = threadIdx.x >> 6, tc = threadIdx.x & 63;
#pragma unroll
  for (int p = 0; p < 16; ++p) {
    int i = p * 4 + tr;
    t[i][tc] = in[(size_t)(r0 + i) * C + c0 + tc];
  }
  __syncthreads();
#pragma unroll
  for (int p = 0; p < 16; ++p) {
    int i = p * 4 + tr;
    out[(size_t)(c0 + i) * ldo + r0 + tc] = f2b(t[tc][i]);
  }
}

// ------------- GEMM (m97 structure + XCD swizzle): C fp32 = A[M][K] @ Bt[N][K] -------------
template <int BM>
__global__ __launch_bounds__(256) void qwen_gemm_bt(const unsigned short* __restrict__ A,
                                                    const unsigned short* __restrict__ Bt,
                                                    float* __restrict__ C,
                                                    int M, int N, int K) {
  __shared__ unsigned short As[BM * 32];
  __shared__ unsigned short Bs[128 * 32];
  constexpr int MR = BM / 32;  // m-repeat per wave (wave owns BM/2 rows)
  const int nwg = gridDim.x * gridDim.y;
  int lin = blockIdx.y * gridDim.x + blockIdx.x;
  if ((nwg & 7) == 0) { int qq = nwg >> 3; lin = (lin & 7) * qq + (lin >> 3); }
  const int bxx = lin % gridDim.x, byy = lin / gridDim.x;
  const int tid = threadIdx.x, lane = tid & 63, w = tid >> 6;
  const int wr = w >> 1, wc = w & 1;
  const int row0 = bxx * BM, col0 = byy * 128;
  f32x4 acc[MR][4] = {};
  const int koff = (lane >> 4) << 3;
  const int rA = wr * (BM / 2) + (lane & 15);
  const int rB = wc * 64 + (lane & 15);
  for (int kt = 0; kt < K; kt += 32) {
#pragma unroll
    for (int c = 0; c < BM / 64; ++c) {
      int off = (c * 256 + tid) * 16;
      int e = off >> 1;
      int r = e >> 5, cc = e & 31;
      gload_lds16(A + (size_t)(row0 + r) * K + kt + cc, (char*)As + off);
    }
#pragma unroll
    for (int c = 0; c < 2; ++c) {
      int off = (c * 256 + tid) * 16;
      int e = off >> 1;
      int r = e >> 5, cc = e & 31;
      gload_lds16(Bt + (size_t)(col0 + r) * K + kt + cc, (char*)Bs + off);
    }
    __syncthreads();
    bfrag aF[MR], bF[4];
#pragma unroll
    for (int m = 0; m < MR; ++m) aF[m] = *(const bfrag*)(As + (rA + m * 16) * 32 + koff);
#pragma unroll
    for (int n = 0; n < 4; ++n) bF[n] = *(const bfrag*)(Bs + (rB + n * 16) * 32 + koff);
#pragma unroll
    for (int m = 0; m < MR; ++m)
#pragma unroll
      for (int n = 0; n < 4; ++n)
        acc[m][n] = __builtin_amdgcn_mfma_f32_16x16x32_bf16(aF[m], bF[n], acc[m][n], 0, 0, 0);
    __syncthreads();
  }
  const int cr = (lane >> 4) << 2;
  const int cc2 = lane & 15;
#pragma unroll
  for (int m = 0; m < MR; ++m)
#pragma unroll
    for (int n = 0; n < 4; ++n) {
      int r = row0 + wr * (BM / 2) + m * 16 + cr;
      int c = col0 + wc * 64 + n * 16 + cc2;
#pragma unroll
      for (int j = 0; j < 4; ++j) C[(size_t)(r + j) * N + c] = acc[m][n][j];
    }
}

// ------------- RoPE epilogue: Q,K -> bf16 [h][s][d] -------------
__global__ __launch_bounds__(256) void qwen_rope_qk(const float* __restrict__ Cqkv,
                                                    const float* __restrict__ cosb,
                                                    const float* __restrict__ sinb,
                                                    const float* __restrict__ qnw,
                                                    const float* __restrict__ knw,
                                                    const float* __restrict__ qden,
                                                    const float* __restrict__ kden,
                                                    unsigned short* __restrict__ Qb,
                                                    unsigned short* __restrict__ Kb) {
  int s = blockIdx.x;
  int t = threadIdx.x;
  const float* row = Cqkv + (size_t)s * 4096;
  const float* cs = cosb + (size_t)s * kHD;
  const float* sn = sinb + (size_t)s * kHD;
#pragma unroll
  for (int rep = 0; rep < 8; ++rep) {
    int idx = rep * 256 + t;
    int h = idx >> 7, d = idx & 127;
    float dn = qden[s * kH + h];
    float v = row[idx] * dn * qnw[d];
    float pv = row[(h << 7) + (d ^ 64)] * dn * qnw[d ^ 64];
    float rot = (d < 64) ? -pv : pv;
    Qb[((size_t)h * kS + s) * kHD + d] = f2b(v * cs[d] + rot * sn[d]);
  }
#pragma unroll
  for (int rep = 0; rep < 4; ++rep) {
    int idx = rep * 256 + t;
    int h = idx >> 7, d = idx & 127;
    float dn = kden[s * kKVH + h];
    float v = row[2048 + idx] * dn * knw[d];
    float pv = row[2048 + (h << 7) + (d ^ 64)] * dn * knw[d ^ 64];
    float rot = (d < 64) ? -pv : pv;
    Kb[((size_t)h * kS + s) * kHD + d] = f2b(v * cs[d] + rot * sn[d]);
  }
}

// ------------- V -> bf16 [kvh][d][s] -------------
__global__ __launch_bounds__(256) void qwen_vtr(const float* __restrict__ Cqkv,
                                                unsigned short* __restrict__ Vt) {
  __shared__ float t[64][65];
  int kvh = blockIdx.x, st = blockIdx.y, dt = blockIdx.z;
  int s0 = st * 64, d0 = dt * 64;
  int tr = threadIdx.x >> 6, tc = threadIdx.x & 63;
#pragma unroll
  for (int p = 0; p < 16; ++p) {
    int i = p * 4 + tr;
    t[i][tc] = Cqkv[(size_t)(s0 + i) * 4096 + 3072 + (kvh << 7) + d0 + tc];
  }
  __syncthreads();
#pragma unroll
  for (int p = 0; p < 16; ++p) {
    int i = p * 4 + tr;
    Vt[(size_t)((kvh << 7) + d0 + i) * kS + s0 + tc] = f2b(t[tc][i]);
  }
}

// ------------- attention: 128-key chunks, 1 raw barrier/chunk, LPT-ordered -------------
// block bid (1024): kvh = bid&7 (XCD-bound), h = kvh*2 + ((bid>>3)&1), qt = 63-(bid>>4).
// Each block: 32 q-rows (q0=qt*32), nch = (qt>>2)+1 chunks of 128 keys.
// QK: wave w owns keys [w*32,+32); PV: wave w owns d in [w*32,+32).
__global__ __launch_bounds__(256, 3) void qwen_attn(const unsigned short* __restrict__ Qb,
                                                    const unsigned short* __restrict__ Kb,
                                                    const unsigned short* __restrict__ Vtb,
                                                    const float* __restrict__ rd,
                                                    unsigned short* __restrict__ AO) {
  __shared__ unsigned short Pl[2][32][136];  // double-buffered P (b128-aligned stride)
  const int bid = blockIdx.x;
  const int kvh = bid & 7;
  const int h = kvh * 2 + ((bid >> 3) & 1);
  const int qt = 63 - (bid >> 4);
  const int q0 = qt * 32;
  const int nch = (qt >> 2) + 1;
  const int tid = threadIdx.x, lane = tid & 63, w = tid >> 6;
  const int l15 = lane & 15, g = lane >> 4;

  // Q fragments in registers
  bfrag qF[2][4];
#pragma unroll
  for (int m = 0; m < 2; ++m)
#pragma unroll
    for (int kc = 0; kc < 4; ++kc)
      qF[m][kc] = *(const bfrag*)(Qb + ((size_t)h * kS + q0 + m * 16 + l15) * kHD +
                                  kc * 32 + g * 8);
  float inv[2][4];
  {
    const float* rdh = rd + (size_t)h * kS + q0;
#pragma unroll
    for (int m = 0; m < 2; ++m)
#pragma unroll
      for (int j = 0; j < 4; ++j) inv[m][j] = 1.0f / rdh[m * 16 + g * 4 + j];
  }
  const unsigned short* Kg = Kb + (size_t)kvh * kS * kHD;
  const unsigned short* Vg = Vtb + ((size_t)kvh * kHD + w * 32) * kS;

  // prologue: chunk-0 K and V into registers
  bfrag kF[2][4], vF[2][4];
#pragma unroll
  for (int n2 = 0; n2 < 2; ++n2)
#pragma unroll
    for (int kc = 0; kc < 4; ++kc)
      kF[n2][kc] = *(const bfrag*)(Kg + (size_t)(w * 32 + n2 * 16 + l15) * kHD +
                                   kc * 32 + g * 8);
#pragma unroll
  for (int n2 = 0; n2 < 2; ++n2)
#pragma unroll
    for (int ks = 0; ks < 4; ++ks)
      vF[n2][ks] = *(const bfrag*)(Vg + (size_t)(n2 * 16 + l15) * kS + ks * 32 + g * 8);

  f32x4 outa[2][2] = {};
  int buf = 0;
#pragma unroll 1
  for (int c = 0; c < nch; ++c) {
    // QK^T (uses kF prefetched last chunk; compiler emits counted vmcnt)
    f32x4 sc[2][2] = {};
#pragma unroll
    for (int m = 0; m < 2; ++m)
#pragma unroll
      for (int n2 = 0; n2 < 2; ++n2)
#pragma unroll
        for (int kc = 0; kc < 4; ++kc)
          sc[m][n2] = __builtin_amdgcn_mfma_f32_16x16x32_bf16(qF[m][kc], kF[n2][kc],
                                                              sc[m][n2], 0, 0, 0);
    // reload kF <- chunk c+1 (in flight across ew + barrier + PV)
    if (c + 1 < nch) {
      const unsigned short* kp = Kg + (size_t)((c + 1) * 128 + w * 32 + l15) * kHD + g * 8;
#pragma unroll
      for (int n2 = 0; n2 < 2; ++n2)
#pragma unroll
        for (int kc = 0; kc < 4; ++kc)
          kF[n2][kc] = *(const bfrag*)(kp + (size_t)n2 * 16 * kHD + kc * 32);
    }
    // elementwise ((s*scale + shift)/rd)^8 -> P bf16
    const bool full = (c * 128 + 127 <= q0);
#pragma unroll
    for (int m = 0; m < 2; ++m)
#pragma unroll
      for (int n2 = 0; n2 < 2; ++n2) {
        const int colc = w * 32 + n2 * 16 + l15;
#pragma unroll
        for (int j = 0; j < 4; ++j) {
          float t = sc[m][n2][j] * kScale;
          if (full) {
            t += 7.0f;
          } else {
            int qg = q0 + m * 16 + g * 4 + j;
            t += ((c * 128 + colc) <= qg) ? 7.0f : 0.0f;
          }
          float y = t * inv[m][j];
          float y2 = y * y, y4 = y2 * y2;
          Pl[buf][m * 16 + g * 4 + j][colc] = f2b(y4 * y4);
        }
      }
    // raw barrier: fence LDS only — global prefetch stays in flight (T4)
    asm volatile("s_waitcnt lgkmcnt(0)" ::: "memory");
    __builtin_amdgcn_s_barrier();
    asm volatile("" ::: "memory");
    // PV: out[q][d] += P[q][key] @ V[key][d]
    bfrag pF[2][4];
#pragma unroll
    for (int m = 0; m < 2; ++m)
#pragma unroll
      for (int ks = 0; ks < 4; ++ks)
        pF[m][ks] = *(const bfrag*)(&Pl[buf][m * 16 + l15][ks * 32 + g * 8]);
#pragma unroll
    for (int m = 0; m < 2; ++m)
#pragma unroll
      for (int n2 = 0; n2 < 2; ++n2)
#pragma unroll
        for (int ks = 0; ks < 4; ++ks)
          outa[m][n2] = __builtin_amdgcn_mfma_f32_16x16x32_bf16(pF[m][ks], vF[n2][ks],
                                                                outa[m][n2], 0, 0, 0);
    // reload vF <- chunk c+1 (in flight across next QK + ew + barrier)
    if (c + 1 < nch) {
      const unsigned short* vp = Vg + (c + 1) * 128 + g * 8;
#pragma unroll
      for (int n2 = 0; n2 < 2; ++n2)
#pragma unroll
        for (int ks = 0; ks < 4; ++ks)
          vF[n2][ks] = *(const bfrag*)(vp + (size_t)(n2 * 16 + l15) * kS + ks * 32);
    }
    buf ^= 1;
  }
  // AO bf16 [s][h*128+d]
#pragma unroll
  for (int m = 0; m < 2; ++m)
#pragma unroll
    for (int n2 = 0; n2 < 2; ++n2)
#pragma unroll
      for (int j = 0; j < 4; ++j)
        AO[(size_t)(q0 + m * 16 + g * 4 + j) * kD + h * 128 + w * 32 + n2 * 16 + l15] =
            f2b(outa[m][n2][j]);
}

extern "C" void kernel_launch(void* const* d_in, const int* in_sizes, int n_in,
                              void* d_out, int out_size, void* d_ws, size_t ws_size,
                              hipStream_t stream) {
  (void)in_sizes; (void)n_in; (void)out_size; (void)ws_size;
  const float* hidden = (const float*)d_in[0];
  const float* cosb   = (const float*)d_in[1];
  const float* sinb   = (const float*)d_in[2];
  const float* qw     = (const float*)d_in[3];
  const float* kw     = (const float*)d_in[4];
  const float* vw     = (const float*)d_in[5];
  const float* ow     = (const float*)d_in[6];
  const float* qnw    = (const float*)d_in[7];
  const float* knw    = (const float*)d_in[8];
  const float* qden   = (const float*)d_in[9];
  const float* kden   = (const float*)d_in[10];
  const float* rd     = (const float*)d_in[11];
  float* out = (float*)d_out;

  char* ws = (char*)d_ws;
  unsigned short* hsb  = (unsigned short*)(ws + 0 * MB);   //  8 MB
  unsigned short* Wt   = (unsigned short*)(ws + 8 * MB);   // 16 MB
  float*          Cqkv = (float*)(ws + 24 * MB);           // 32 MB
  unsigned short* Qb   = (unsigned short*)(ws + 56 * MB);  //  8 MB
  unsigned short* Kb   = (unsigned short*)(ws + 64 * MB);  //  4 MB
  unsigned short* Vtb  = (unsigned short*)(ws + 68 * MB);  //  4 MB
  unsigned short* AO   = (unsigned short*)(ws + 72 * MB);  //  8 MB
  unsigned short* Ot   = (unsigned short*)(ws + 80 * MB);  //  8 MB

  qwen_cast_bf16<<<4096, 256, 0, stream>>>(hidden, hsb, 2048 * 2048 / 4);
  qwen_tw<<<dim3(32, 32), 256, 0, stream>>>(qw, 2048, 2048, Wt, 2048);
  qwen_tw<<<dim3(16, 32), 256, 0, stream>>>(kw, 2048, 1024, Wt + (size_t)2048 * 2048, 2048);
  qwen_tw<<<dim3(16, 32), 256, 0, stream>>>(vw, 2048, 1024, Wt + (size_t)3072 * 2048, 2048);
  qwen_tw<<<dim3(32, 32), 256, 0, stream>>>(ow, 2048, 2048, Ot, 2048);
  qwen_gemm_bt<128><<<dim3(16, 32), 256, 0, stream>>>(hsb, Wt, Cqkv, 2048, 4096, 2048);
  qwen_rope_qk<<<2048, 256, 0, stream>>>(Cqkv, cosb, sinb, qnw, knw, qden, kden, Qb, Kb);
  qwen_vtr<<<dim3(8, 32, 2), 256, 0, stream>>>(Cqkv, Vtb);
  qwen_attn<<<1024, 256, 0, stream>>>(Qb, Kb, Vtb, rd, AO);
  qwen_gemm_bt<64><<<dim3(32, 16), 256, 0, stream>>>(AO, Ot, out, 2048, 2048, 2048);
}